// Round 7
// baseline (196.765 us; speedup 1.0000x reference)
//
#include <hip/hip_runtime.h>
#include <cmath>

#define B_   128
#define H_   256
#define W_   256
#define WC_  129
#define L_   182
#define NG_  33    // column groups per image in pass2 (4 cols/group * 33 >= 129)
#define PI_F 3.14159265358979f

// ---------------------------------------------------------------------------
// Wave-synchronous 256-pt DIF FFT, OLD layout (s = l + 64j), used by pass2.
// Lane l slot j = x[l + 64*j]; output storage q = l + 64j holds X[bitrev8(q)].
// ---------------------------------------------------------------------------
__device__ __forceinline__ void fft256_wave(float vr[4], float vi[4], int l) {
  float c0, s0;
  __sincosf(-2.f * PI_F * (float)l / 256.f, &s0, &c0);  // w0 = W256^l
  {
    float ur = vr[0] + vr[2], ui = vi[0] + vi[2];
    float dr = vr[0] - vr[2], di = vi[0] - vi[2];
    vr[0] = ur; vi[0] = ui;
    vr[2] = dr * c0 - di * s0; vi[2] = dr * s0 + di * c0;
    float c1 = s0, s1 = -c0;
    ur = vr[1] + vr[3]; ui = vi[1] + vi[3];
    dr = vr[1] - vr[3]; di = vi[1] - vi[3];
    vr[1] = ur; vi[1] = ui;
    vr[3] = dr * c1 - di * s1; vi[3] = dr * s1 + di * c1;
  }
  {
    float c2 = c0 * c0 - s0 * s0, s2 = 2.f * c0 * s0;
    float ur = vr[0] + vr[1], ui = vi[0] + vi[1];
    float dr = vr[0] - vr[1], di = vi[0] - vi[1];
    vr[0] = ur; vi[0] = ui;
    vr[1] = dr * c2 - di * s2; vi[1] = dr * s2 + di * c2;
    ur = vr[2] + vr[3]; ui = vi[2] + vi[3];
    dr = vr[2] - vr[3]; di = vi[2] - vi[3];
    vr[2] = ur; vi[2] = ui;
    vr[3] = dr * c2 - di * s2; vi[3] = dr * s2 + di * c2;
  }
  #pragma unroll
  for (int h = 32; h >= 1; h >>= 1) {
    int i = l & (h - 1);
    float c, s;
    __sincosf(-PI_F * (float)i / (float)h, &s, &c);
    bool up = (l & h) != 0;
    float cc = up ? c : 1.f;
    float ss = up ? s : 0.f;
    float sgn = up ? -1.f : 1.f;
    #pragma unroll
    for (int j = 0; j < 4; ++j) {
      float br = __shfl_xor(vr[j], h, 64);
      float bi = __shfl_xor(vi[j], h, 64);
      float tr = fmaf(sgn, vr[j], br);
      float ti = fmaf(sgn, vi[j], bi);
      vr[j] = tr * cc - ti * ss;
      vi[j] = tr * ss + ti * cc;
    }
  }
}

// ---------------------------------------------------------------------------
// NEW-layout (s = 4l + j) cross-lane DIF stage for 4 FFTs sharing twiddles.
// Sub-FFT size N' = 8h; twiddle W_{N'}^{s mod 4h} = e^{-i*pi*(l&(h-1))/h}
// * e^{-i*pi*j/(4h)}. CT/ST = cos/sin(pi/(4h)).
// ---------------------------------------------------------------------------
__device__ __forceinline__ void stage4(float (&vr)[4][4], float (&vi)[4][4],
                                       int l, int h, float CT, float ST) {
  int i = l & (h - 1);
  float s, c;
  __sincosf(-PI_F * (float)i / (float)h, &s, &c);
  float wr[4], wi[4];
  wr[0] = c;                    wi[0] = s;
  wr[1] = c * CT + s * ST;      wi[1] = s * CT - c * ST;
  wr[2] = wr[1] * CT + wi[1] * ST; wi[2] = wi[1] * CT - wr[1] * ST;
  wr[3] = wr[2] * CT + wi[2] * ST; wi[3] = wi[2] * CT - wr[2] * ST;
  bool up = (l & h) != 0;
  float sgn = up ? -1.f : 1.f;
  #pragma unroll
  for (int f = 0; f < 4; ++f) {
    #pragma unroll
    for (int j = 0; j < 4; ++j) {
      float br = __shfl_xor(vr[f][j], h, 64);
      float bi = __shfl_xor(vi[f][j], h, 64);
      float tr = fmaf(sgn, vr[f][j], br);
      float ti = fmaf(sgn, vi[f][j], bi);
      float cc = up ? wr[j] : 1.f;
      float ss = up ? wi[j] : 0.f;
      vr[f][j] = tr * cc - ti * ss;
      vi[f][j] = tr * ss + ti * cc;
    }
  }
}

__device__ __forceinline__ float4 luma4(float4 r, float4 g, float4 b) {
  float4 o;
  o.x = fmaf(0.299f, r.x, fmaf(0.587f, g.x, 0.114f * b.x));
  o.y = fmaf(0.299f, r.y, fmaf(0.587f, g.y, 0.114f * b.y));
  o.z = fmaf(0.299f, r.z, fmaf(0.587f, g.z, 0.114f * b.z));
  o.w = fmaf(0.299f, r.w, fmaf(0.587f, g.w, 0.114f * b.w));
  return o;
}

#define P1_STRIDE 259  // float2 LDS stride; transpose read = ~4-way (measured cheap)

// Pass 1: luma + row-pair real FFT. 256 thr = 4 waves; each wave runs 4 FFTs
// (shared twiddles), each FFT = one row-pair packed re+i*im. Inputs load as
// float4 (lane-contiguous s=4l+j layout). LDS slot swizzle keeps the old
// conflict-free write pattern; transpose unpacks A/B via conjugate symmetry
// and stores inter[b][k][row] as coalesced float4 row-pairs.
__global__ __launch_bounds__(256) void pass1_kernel(
    const float* __restrict__ data, float4* __restrict__ inter4) {
  __shared__ float2 tile[16 * P1_STRIDE];
  int tid = threadIdx.x;
  int w = tid >> 6, l = tid & 63;
  int b = blockIdx.x >> 3;
  int rg = blockIdx.x & 7;
  int row0 = rg * 32;
  const float* img = data + ((size_t)b * 3) * (H_ * W_);
  float vr[4][4], vi[4][4];
  // ---- loads in 2 batches of 12 independent float4 ----
  #pragma unroll
  for (int half = 0; half < 2; ++half) {
    float4 ra[2], ga[2], ba[2], rb[2], gb[2], bb[2];
    #pragma unroll
    for (int e = 0; e < 2; ++e) {
      int f = half * 2 + e;
      int rowA = row0 + 2 * (4 * w + f);
      const float* pA = img + (size_t)rowA * W_ + 4 * l;
      ra[e] = *(const float4*)(pA);
      ga[e] = *(const float4*)(pA + H_ * W_);
      ba[e] = *(const float4*)(pA + 2 * H_ * W_);
      rb[e] = *(const float4*)(pA + W_);
      gb[e] = *(const float4*)(pA + H_ * W_ + W_);
      bb[e] = *(const float4*)(pA + 2 * H_ * W_ + W_);
    }
    #pragma unroll
    for (int e = 0; e < 2; ++e) {
      int f = half * 2 + e;
      float4 A = luma4(ra[e], ga[e], ba[e]);
      float4 Bv = luma4(rb[e], gb[e], bb[e]);
      vr[f][0] = A.x; vr[f][1] = A.y; vr[f][2] = A.z; vr[f][3] = A.w;
      vi[f][0] = Bv.x; vi[f][1] = Bv.y; vi[f][2] = Bv.z; vi[f][3] = Bv.w;
    }
  }
  // ---- 6 cross-lane stages (shared twiddles across the 4 FFTs) ----
  stage4(vr, vi, l, 32, 0.9996988187f, 0.0245412285f);  // N'=256
  stage4(vr, vi, l, 16, 0.9987954562f, 0.0490676743f);  // N'=128
  stage4(vr, vi, l,  8, 0.9951847267f, 0.0980171403f);  // N'=64
  stage4(vr, vi, l,  4, 0.9807852804f, 0.1950903220f);  // N'=32
  stage4(vr, vi, l,  2, 0.9238795325f, 0.3826834324f);  // N'=16
  stage4(vr, vi, l,  1, 0.7071067812f, 0.7071067812f);  // N'=8
  // ---- in-lane stages N'=4 (tw {1,-i}) and N'=2 (tw 1) ----
  #pragma unroll
  for (int f = 0; f < 4; ++f) {
    float u0r = vr[f][0] + vr[f][2], u0i = vi[f][0] + vi[f][2];
    float v0r = vr[f][0] - vr[f][2], v0i = vi[f][0] - vi[f][2];
    float u1r = vr[f][1] + vr[f][3], u1i = vi[f][1] + vi[f][3];
    float d1r = vr[f][1] - vr[f][3], d1i = vi[f][1] - vi[f][3];
    float v1r = d1i, v1i = -d1r;                 // (x1-x3)*(-i)
    vr[f][0] = u0r + u1r; vi[f][0] = u0i + u1i;
    vr[f][1] = u0r - u1r; vi[f][1] = u0i - u1i;
    vr[f][2] = v0r + v1r; vi[f][2] = v0i + v1i;
    vr[f][3] = v0r - v1r; vi[f][3] = v0i - v1i;
    // storage s = 4l+j holds X[bitrev8(s)]; LDS slot = l + 64j (swizzle)
    int p = 4 * w + f;
    #pragma unroll
    for (int j = 0; j < 4; ++j)
      tile[p * P1_STRIDE + l + 64 * j] = make_float2(vr[f][j], vi[f][j]);
  }
  __syncthreads();
  // A(k) = (Z(k)+conj(Z(N-k)))/2 ; B(k) = (Z(k)-conj(Z(N-k)))/(2i)
  for (int fi = tid; fi < WC_ * 16; fi += 256) {
    int k = fi >> 4;
    int p = fi & 15;
    int q  = (int)(__brev((unsigned)k) >> 24);
    int qn = (int)(__brev((unsigned)((256 - k) & 255)) >> 24);
    int qs  = (q >> 2)  + 64 * (q & 3);   // swizzled LDS slot of storage q
    int qns = (qn >> 2) + 64 * (qn & 3);
    float2 Zk  = tile[p * P1_STRIDE + qs];
    float2 Znk = tile[p * P1_STRIDE + qns];
    float4 o;
    o.x = 0.5f * (Zk.x + Znk.x);   // A.re
    o.y = 0.5f * (Zk.y - Znk.y);   // A.im
    o.z = 0.5f * (Zk.y + Znk.y);   // B.re
    o.w = 0.5f * (Znk.x - Zk.x);   // B.im
    inter4[((((size_t)b * WC_ + k) * H_ + row0) >> 1) + p] = o;
  }
}

// Pass 2: column FFT + log-power + radial binning into per-block LDS bins,
// flushed with plain stores to partial[b][g][L]. Blocks with b==0 also
// produce the radial count histogram (batch-independent) into cntpart[g][L].
__global__ __launch_bounds__(256) void pass2_kernel(
    const float2* __restrict__ inter, const int* __restrict__ radius,
    float* __restrict__ partial, float* __restrict__ cntpart) {
  __shared__ float lbins[L_];
  __shared__ float lcnt[L_];
  int tid = threadIdx.x;
  int wv = tid >> 6, l = tid & 63;
  int b = blockIdx.x / NG_;
  int g = blockIdx.x - b * NG_;
  int k = g * 4 + wv;
  bool do_cnt = (b == 0);
  for (int i = tid; i < L_; i += 256) lbins[i] = 0.f;
  if (do_cnt)
    for (int i = tid; i < L_; i += 256) lcnt[i] = 0.f;
  __syncthreads();
  if (k < WC_) {
    const float2* p = inter + ((size_t)b * WC_ + k) * H_;
    float vr[4], vi[4];
    #pragma unroll
    for (int j = 0; j < 4; ++j) {
      float2 v = p[l + 64 * j];
      vr[j] = v.x; vi[j] = v.y;
    }
    fft256_wave(vr, vi, l);
    int rb = 4 * (int)(__brev((unsigned)l) >> 26);
    #pragma unroll
    for (int j = 0; j < 4; ++j) {
      int rf = rb + ((j == 1) ? 2 : (j == 2) ? 1 : j);  // bitrev2(j)
      int bin = radius[rf * WC_ + k];
      float pw = vr[j] * vr[j] + vi[j] * vi[j];
      float val = 20.f * __logf(pw + 1e-8f);
      atomicAdd(&lbins[bin], val);
      if (do_cnt) atomicAdd(&lcnt[bin], 1.f);
    }
  }
  __syncthreads();
  float* pp = partial + ((size_t)b * NG_ + g) * L_;
  for (int i = tid; i < L_; i += 256) pp[i] = lbins[i];
  if (do_cnt) {
    float* cp = cntpart + (size_t)g * L_;
    for (int i = tid; i < L_; i += 256) cp[i] = lcnt[i];
  }
}

// One block per batch sample: reduce 33 value+count partials, segment mean,
// min-max normalize, L1 vs mean. Plain store of per-sample loss.
__global__ __launch_bounds__(256) void loss_kernel(
    const float* __restrict__ partial, const float* __restrict__ cntpart,
    const float* __restrict__ mean, float* __restrict__ lpart) {
  int b = blockIdx.x;
  int t = threadIdx.x;
  __shared__ float prof[L_];
  __shared__ float red[256];
  float acc = 0.f, csum = 0.f;
  if (t < L_) {
    const float* pb = partial + (size_t)b * NG_ * L_;
    #pragma unroll 3
    for (int g = 0; g < NG_; ++g) {
      acc  += pb[g * L_ + t];
      csum += cntpart[g * L_ + t];
    }
    prof[t] = acc / csum;
  }
  __syncthreads();
  red[t] = (t < L_) ? prof[t] : INFINITY;
  __syncthreads();
  for (int s = 128; s > 0; s >>= 1) {
    if (t < s) red[t] = fminf(red[t], red[t + s]);
    __syncthreads();
  }
  float mn = red[0];
  __syncthreads();
  red[t] = (t < L_) ? (prof[t] - mn) : -INFINITY;
  __syncthreads();
  for (int s = 128; s > 0; s >>= 1) {
    if (t < s) red[t] = fmaxf(red[t], red[t + s]);
    __syncthreads();
  }
  float mx = red[0];
  __syncthreads();
  red[t] = (t < L_) ? fabsf((prof[t] - mn) / mx - mean[t]) : 0.f;
  __syncthreads();
  for (int s = 128; s > 0; s >>= 1) {
    if (t < s) red[t] += red[t + s];
    __syncthreads();
  }
  if (t == 0) lpart[b] = red[0];
}

// Final: one wave sums the 128 per-sample losses, plain store to out.
__global__ __launch_bounds__(64) void final_kernel(
    const float* __restrict__ lpart, float* __restrict__ out) {
  int l = threadIdx.x;
  float v = lpart[l] + lpart[l + 64];
  #pragma unroll
  for (int h = 32; h >= 1; h >>= 1) v += __shfl_xor(v, h, 64);
  if (l == 0) out[0] = v;
}

extern "C" void kernel_launch(void* const* d_in, const int* in_sizes, int n_in,
                              void* d_out, int out_size, void* d_ws, size_t ws_size,
                              hipStream_t stream) {
  const float* data   = (const float*)d_in[0];  // [128,3,256,256] f32
  const float* mean   = (const float*)d_in[1];  // [182] f32
  const int*   radius = (const int*)d_in[2];    // [256,129] i32
  float* out = (float*)d_out;                   // scalar f32

  float2* inter = (float2*)d_ws;                          // [B][WC][H] complex
  size_t inter_bytes = (size_t)B_ * WC_ * H_ * sizeof(float2);
  float* partial = (float*)((char*)d_ws + inter_bytes);   // [B][NG][L]
  float* cntpart = partial + (size_t)B_ * NG_ * L_;       // [NG][L]
  float* lpart   = cntpart + (size_t)NG_ * L_;            // [B]

  pass1_kernel<<<B_ * 8, 256, 0, stream>>>(data, (float4*)inter);
  pass2_kernel<<<B_ * NG_, 256, 0, stream>>>(inter, radius, partial, cntpart);
  loss_kernel<<<B_, 256, 0, stream>>>(partial, cntpart, mean, lpart);
  final_kernel<<<1, 64, 0, stream>>>(lpart, out);
}